// Round 10
// baseline (524.273 us; speedup 1.0000x reference)
//
#include <hip/hip_runtime.h>

#define GH 135
#define GW 240
#define HH 1080
#define WW 1920
#define HWPX (HH*WW)
#define NP 12
#define IT 6               // anchor block-rows per WG
#define JT 6               // anchor blocks (j) per WG
#define NTG 2              // anchor TRIPLES per it-row (3 blocks/thread)
#define NIG 23             // ceil(GH/IT), last strip ragged (3 valid rows)
#define NJG 40             // GW/JT
#define TROWS (IT+8)       // 14 staged target block-rows
#define TBLK (JT+8)        // 14 staged target blocks per dy-row
#define DSTR (TBLK*64+4)   // 900 dw: 16B-aligned; dr*900 %32 = 4*dr (quad shift/row)
#define UNITS_ROW (TBLK*16)// 224 16B-units per dy-row
#define UNITS_TOT (TROWS*UNITS_ROW) // 3136
#define NTHR 256
#define NACT 216           // 9 dy * (6 it * 2 tg * 2 yh)  -> 84% active (r5-proven)
#define TT_DW (TROWS*DSTR) // 12600 dw = 50400 B -> 3 WG/CU (r5-proven envelope)
#define NWG (NIG*NJG)      // 920 = 8*115 (XCD-exact)

// r9 lesson: 3-anchor windows must NOT cut the active fraction. This geometry
// keeps NACT=216/256 AND 3 WG/CU AND 3-anchor reuse: square 6x6 tile,
// halo/anchor 8.33 -> 5.44, LDS reads/anchor x0.73, NWG 1360 -> 920.
// Swizzled storage (bijective involution, proven r5):
//   stored(blk,y,xh) = blk*64 + ((y*8+xh) ^ 4*kb ^ 16*(y>>2)), kb=(blk>>1)&7
// Write side LINEAR (zero write conflicts); global src inverse-swizzled.

// 8-px fp32 chain + f64 accumulate (argmin-exact vs np reference, proven r1-r9)
#define CHAIN(AV0, AV1, T0, T1, ACC) do { \
    float _d = (AV0).x - (T0).x; float _s = _d*_d; \
    _d = (AV0).y - (T0).y; _s = fmaf(_d,_d,_s); \
    _d = (AV0).z - (T0).z; _s = fmaf(_d,_d,_s); \
    _d = (AV0).w - (T0).w; _s = fmaf(_d,_d,_s); \
    _d = (AV1).x - (T1).x; _s = fmaf(_d,_d,_s); \
    _d = (AV1).y - (T1).y; _s = fmaf(_d,_d,_s); \
    _d = (AV1).z - (T1).z; _s = fmaf(_d,_d,_s); \
    _d = (AV1).w - (T1).w; _s = fmaf(_d,_d,_s); \
    (ACC) += (double)_s; } while(0)

__global__ void __launch_bounds__(NTHR, 3)
hbma_cost_kernel(const float* __restrict__ A, const float* __restrict__ T,
                 int* __restrict__ bestidx) {
    extern __shared__ float lds[];
    float* Tt = lds;

    // XCD swizzle: 920 WGs = 8 XCDs x 115
    const int lin = blockIdx.x;
    const int g   = (lin & 7) * (NWG / 8) + (lin >> 3);
    const int ig  = g % NIG, jg = g / NIG;
    const int i0  = ig * IT;
    const int j0  = jg * JT;

    const int tid = threadIdx.x;
    const int dy  = tid / 24;          // 0..8 for active threads
    const int rem = tid % 24;
    const int it  = rem >> 2;          // 0..5
    const int r2  = rem & 3;
    const int tg  = r2 >> 1;           // 0..1 (anchor triple)
    const int yh  = r2 & 1;            // y-half
    const bool act = (tid < NACT);
    const int i   = i0 + it;           // may be >= GH on last strip (guarded)
    const int gi  = i + dy - 4;
    const bool dyValid = act && (i < GH) && (gi >= 0) && (gi < GH);
    const int dr  = it + dy;           // staged row index 0..13
    const int jb0 = j0 + 3 * tg;       // first anchor block of this thread

    // per-p read XOR (window base 3*tg may be odd); static-indexed -> registers
    int xq2[11];
#pragma unroll
    for (int p = 0; p < 11; ++p)
        xq2[p] = ((((3 * tg + p) >> 1) & 7) * 4) ^ (yh << 4);

    double acc[3][9];
#pragma unroll
    for (int a = 0; a < 3; ++a)
#pragma unroll
        for (int d = 0; d < 9; ++d) acc[a][d] = 0.0;

    const int gy0 = (i0 - 4) * 8;
    const int gx0 = (j0 - 4) * 8;

    for (int q = 0; q < NP; ++q) {
        const float* Tq = T + (size_t)q * HWPX;
        const float* Aq = A + (size_t)q * HWPX;
        __syncthreads();               // prev compute done before LDS overwrite
        // ---- stage target halo: LINEAR LDS writes, inverse-swizzled global src ----
        for (int w = tid; w < UNITS_TOT; w += NTHR) {
            const int dyr = w / UNITS_ROW;
            const int u   = w - dyr * UNITS_ROW;    // 16B unit within dy-row
            const int blk = u >> 4, v = u & 15;
            const int kb  = (blk >> 1) & 7;
            const int yh2 = v >> 3;
            const int m3  = (v & 7) ^ kb ^ (yh2 << 2);
            const int y   = (yh2 << 2) + (m3 >> 1);
            const int xh4 = m3 & 1;
            const int gy  = gy0 + dyr * 8 + y;
            const int gx  = gx0 + blk * 8 + xh4 * 4;
            if ((unsigned)gy < (unsigned)HH && (unsigned)gx < (unsigned)WW) {
                *(float4*)(Tt + dyr * DSTR + u * 4) =
                    *(const float4*)(Tq + (size_t)gy * WW + gx);
            }
        }
        __syncthreads();
        // ---- SSD: sliding 11-block window serves 3 anchors x 9 dx ----
        if (dyValid) {
            const float* tb = Tt + dr * DSTR + (3 * tg) * 64 + yh * 32;
#pragma unroll
            for (int yi = 0; yi < 4; ++yi) {
                // anchor rows for this yi (6 f4 live; L1-hot, 9x dy-redundant)
                float4 aw[3][2];
#pragma unroll
                for (int a = 0; a < 3; ++a) {
                    const float* row = Aq + (size_t)(jb0 + a) * 8
                                     + (size_t)(i * 8 + yh * 4 + yi) * WW;
                    aw[a][0] = *(const float4*)(row);
                    aw[a][1] = *(const float4*)(row + 4);
                }
                // p-chunks of 4/4/3: bounded tw pressure, deep ds ILP
#pragma unroll
                for (int ph = 0; ph < 3; ++ph) {
                    const int pc = (ph < 2) ? 4 : 3;
                    float4 tw0[4], tw1[4];
#pragma unroll
                    for (int pp = 0; pp < 4; ++pp) {
                        if (pp < pc) {
                            const int p  = ph * 4 + pp;
                            const int o0 = (yi * 8) ^ xq2[p];
                            tw0[pp] = *(const float4*)(tb + p * 64 + o0);
                            tw1[pp] = *(const float4*)(tb + p * 64 + (o0 ^ 4));
                        }
                    }
#pragma unroll
                    for (int pp = 0; pp < 4; ++pp) {
                        if (pp < pc) {
                            const int p = ph * 4 + pp;
#pragma unroll
                            for (int a = 0; a < 3; ++a) {
                                const int dxi = p - a;
                                if (dxi >= 0 && dxi < 9)
                                    CHAIN(aw[a][0], aw[a][1], tw0[pp], tw1[pp], acc[a][dxi]);
                            }
                        }
                    }
                }
            }
        }
    }
    // ---- y-half merge via LDS (aliases Tt, barrier-protected) ----
    __syncthreads();
    double* yred = (double*)lds;                     // 108 groups * 27 f64 = 5832 dw
    const int grpId = (it * NTG + tg) * 9 + dy;      // 0..107
    if (act && yh == 1) {
        double* d = yred + grpId * 27;
#pragma unroll
        for (int a = 0; a < 3; ++a)
#pragma unroll
            for (int k = 0; k < 9; ++k) d[a * 9 + k] = acc[a][k];
    }
    __syncthreads();
    double* redc = (double*)(lds + 8192);            // 324 f64 = 648 dw
    int*    redk = (int*)(lds + 8192 + 648);         // 324 int
    if (act && yh == 0) {
        const double* d = yred + grpId * 27;
#pragma unroll
        for (int a = 0; a < 3; ++a)
#pragma unroll
            for (int k = 0; k < 9; ++k) acc[a][k] += d[a * 9 + k];
        // stage-1 argmin over dx (ascending, strict < -> first-k ties)
#pragma unroll
        for (int a = 0; a < 3; ++a) {
            double bc = 1e300; int bk = -1;
            const int jb = jb0 + a;
#pragma unroll
            for (int dxi = 0; dxi < 9; ++dxi) {
                const int gj = jb + dxi - 4;
                if (dyValid && gj >= 0 && gj < GW && acc[a][dxi] < bc) {
                    bc = acc[a][dxi]; bk = dy * 9 + dxi;
                }
            }
            redc[(it * 9 + dy) * JT + 3 * tg + a] = bc;
            redk[(it * 9 + dy) * JT + 3 * tg + a] = bk;
        }
    }
    __syncthreads();
    // ---- stage-2 argmin over dy (ascending, strict <) ----
    if (tid < IT * JT) {
        const int it2 = tid / JT, jt = tid % JT;
        if (i0 + it2 < GH) {
            double c = 1e300; int k = -1;
#pragma unroll
            for (int dyi = 0; dyi < 9; ++dyi) {
                const double v = redc[(it2 * 9 + dyi) * JT + jt];
                if (v < c) { c = v; k = redk[(it2 * 9 + dyi) * JT + jt]; }
            }
            const int dyi = k / 9, dxi = k % 9;
            const int bi = i0 + it2 + dyi - 4;
            const int bj = j0 + jt + dxi - 4;
            bestidx[(i0 + it2) * GW + j0 + jt] = (bi << 8) | bj;
        }
    }
}

__global__ void __launch_bounds__(256) hbma_gather_kernel(const float* __restrict__ A,
                                                          const int* __restrict__ bestidx,
                                                          float* __restrict__ out) {
    const int tid = blockIdx.x * 256 + threadIdx.x;
    const int q   = tid / (HWPX / 4);
    const int rem = tid % (HWPX / 4);
    const int py  = rem / (WW / 4);
    const int c4  = rem % (WW / 4);
    const int i = py >> 3, y = py & 7;
    const int j = c4 >> 1, xh = (c4 & 1) * 4;
    const int idx = bestidx[i * GW + j];
    const int bi = idx >> 8, bj = idx & 255;
    const float4 v = *(const float4*)(A + (size_t)q * HWPX + (size_t)(bi * 8 + y) * WW + bj * 8 + xh);
    *(float4*)(out + (size_t)q * HWPX + (size_t)py * WW + c4 * 4) = v;
}

extern "C" void kernel_launch(void* const* d_in, const int* in_sizes, int n_in,
                              void* d_out, int out_size, void* d_ws, size_t ws_size,
                              hipStream_t stream) {
    const float* A = (const float*)d_in[0];
    const float* T = (const float*)d_in[1];
    float* out = (float*)d_out;
    int* bestidx = (int*)d_ws;

    hipFuncSetAttribute((const void*)hbma_cost_kernel,
                        hipFuncAttributeMaxDynamicSharedMemorySize, TT_DW * 4);

    hipLaunchKernelGGL(hbma_cost_kernel, dim3(NWG), dim3(NTHR), TT_DW * 4, stream,
                       A, T, bestidx);

    const int total4 = (NP * HWPX) / 4;
    hipLaunchKernelGGL(hbma_gather_kernel, dim3(total4 / 256), dim3(256), 0, stream,
                       A, bestidx, out);
}

// Round 11
// 253.167 us; speedup vs baseline: 2.0709x; 2.0709x over previous
//
#include <hip/hip_runtime.h>

#define GH 135
#define GW 240
#define HH 1080
#define WW 1920
#define HWPX (HH*WW)
#define NP 12
#define IT 2               // anchor block-rows per WG (i-strip)
#define JT 12              // anchor blocks (j) per WG
#define NBG 6              // anchor pairs per it-row
#define NIG 68             // ceil(GH/IT)
#define NJG 20             // GW/JT
#define TROWS (IT+8)       // 10 staged target block-rows
#define TBLK (JT+8)        // 20 staged target blocks per dy-row
#define DSTR (TBLK*64+4)   // 1284 dw: 16B-aligned; dr*1284 %32 = 4*dr (quad shift/row)
#define UNITS_ROW (TBLK*16)// 320 16B-units per dy-row (= exactly 5 waves: 64|320)
#define UNITS_TOT (TROWS*UNITS_ROW) // 3200
#define NTHR 256
#define NACT 216           // 9 dy * (2 it * 6 bg * 2 yh)
#define TT_DW (TROWS*DSTR) // 12840 dw = 51360 B -> 3 WG/CU (proven r5)
#define NWG (NIG*NJG)      // 1360 = 8*170 (XCD-exact)

// OCCUPANCY LAW (fit from r5/r7/r8/r9/r10): VGPR cap = 256/min_waves_per_EU;
// resident waves/SIMD = floor(256/VGPR_used). r5's 84 regs -> 3 waves/SIMD ->
// 3 WG/CU. This kernel = r5 verbatim EXCEPT staging goes through
// __builtin_amdgcn_global_load_lds (async DMA, no VGPR round-trip, no
// ds_writes). Dest satisfies the wave-uniform-base+lane*16 rule: 320 units/row
// = 5 full waves, row bases 16B-aligned, loop-tail branch is wave-uniform.
// OOB lanes use CLAMPED sources (garbage lands only in argmin-masked slots).
// Swizzled storage (bijective involution, proven r5):
//   stored(blk,y,xh) = blk*64 + ((y*8+xh) ^ 4*kb ^ 16*(y>>2)), kb=(blk>>1)&7

// 8-px fp32 chain + f64 accumulate (argmin-exact vs np reference, proven r1-r10)
#define CHAIN(AV0, AV1, T0, T1, ACC) do { \
    float _d = (AV0).x - (T0).x; float _s = _d*_d; \
    _d = (AV0).y - (T0).y; _s = fmaf(_d,_d,_s); \
    _d = (AV0).z - (T0).z; _s = fmaf(_d,_d,_s); \
    _d = (AV0).w - (T0).w; _s = fmaf(_d,_d,_s); \
    _d = (AV1).x - (T1).x; _s = fmaf(_d,_d,_s); \
    _d = (AV1).y - (T1).y; _s = fmaf(_d,_d,_s); \
    _d = (AV1).z - (T1).z; _s = fmaf(_d,_d,_s); \
    _d = (AV1).w - (T1).w; _s = fmaf(_d,_d,_s); \
    (ACC) += (double)_s; } while(0)

__device__ __forceinline__ void async_copy16(const float* gp, float* lp) {
#if __has_builtin(__builtin_amdgcn_global_load_lds)
    __builtin_amdgcn_global_load_lds(
        (const __attribute__((address_space(1))) void*)gp,
        (__attribute__((address_space(3))) void*)lp, 16, 0, 0);
#else
    *(float4*)lp = *(const float4*)gp;
#endif
}

__global__ void __launch_bounds__(NTHR, 3)
hbma_cost_kernel(const float* __restrict__ A, const float* __restrict__ T,
                 int* __restrict__ bestidx) {
    extern __shared__ float lds[];
    float* Tt = lds;

    // XCD swizzle: 1360 WGs = 8 XCDs x 170
    const int lin = blockIdx.x;
    const int g   = (lin & 7) * (NWG / 8) + (lin >> 3);
    const int ig  = g % NIG, jg = g / NIG;
    const int i0  = ig * IT;
    const int j0  = jg * JT;

    const int tid = threadIdx.x;
    const int dy  = tid / 24;          // 0..8
    const int rem = tid % 24;
    const int it  = rem / 12;          // 0..1
    const int r2  = rem % 12;
    const int bg  = r2 >> 1;           // 0..5 (anchor pair)
    const int yh  = r2 & 1;            // y-half
    const bool act = (tid < NACT);
    const int i   = i0 + it;
    const int gi  = i + dy - 4;
    const bool dyValid = act && (i < GH) && (gi >= 0) && (gi < GH);
    const int dr  = it + dy;           // staged row index 0..9

    int xq[5];                         // per p-pair h: 4*((bg+h)&7) ^ 16*yh
#pragma unroll
    for (int h = 0; h < 5; ++h) xq[h] = (((bg + h) & 7) * 4) ^ (yh << 4);

    double acc0[9], acc1[9];
#pragma unroll
    for (int d = 0; d < 9; ++d) { acc0[d] = 0.0; acc1[d] = 0.0; }

    const int gy0 = (i0 - 4) * 8;
    const int gx0 = (j0 - 4) * 8;

    for (int q = 0; q < NP; ++q) {
        const float* Tq = T + (size_t)q * HWPX;
        const float* Aq = A + (size_t)q * HWPX;
        __syncthreads();               // prev compute done before LDS overwrite
        // ---- stage target halo: async global->LDS DMA (linear dest units),
        //      inverse-swizzled + clamped global src; no regs, no ds_writes ----
        for (int w = tid; w < UNITS_TOT; w += NTHR) {
            const int dyr = w / UNITS_ROW;
            const int u   = w - dyr * UNITS_ROW;    // 16B unit within dy-row
            const int blk = u >> 4, v = u & 15;
            const int kb  = (blk >> 1) & 7;
            const int yh2 = v >> 3;
            const int m3  = (v & 7) ^ kb ^ (yh2 << 2);
            const int y   = (yh2 << 2) + (m3 >> 1);
            const int xh4 = m3 & 1;
            int gy = gy0 + dyr * 8 + y;
            int gx = gx0 + blk * 8 + xh4 * 4;
            gy = min(max(gy, 0), HH - 1);           // clamp: all lanes active,
            gx = min(max(gx, 0), WW - 4);           // garbage slots argmin-masked
            async_copy16(Tq + (size_t)gy * WW + gx, Tt + dyr * DSTR + u * 4);
        }
        // ---- anchor rows -> registers (issue overlaps in-flight DMA) ----
        float4 ar[2][4][2];
        if (act && i < GH) {
#pragma unroll
            for (int a2 = 0; a2 < 2; ++a2) {
                const float* ap = Aq + (size_t)(j0 + 2 * bg + a2) * 8;
#pragma unroll
                for (int yi = 0; yi < 4; ++yi) {
                    const float* row = ap + (size_t)(i * 8 + yh * 4 + yi) * WW;
                    ar[a2][yi][0] = *(const float4*)(row);
                    ar[a2][yi][1] = *(const float4*)(row + 4);
                }
            }
        }
        __syncthreads();               // compiler drains vmcnt(0) here: DMA landed
        // ---- SSD: sliding 10-block window serves 2 anchors x 9 dx ----
        if (dyValid) {
            const float* tb = Tt + dr * DSTR + bg * 128 + yh * 32;
#pragma unroll
            for (int yi = 0; yi < 4; ++yi) {
#pragma unroll
                for (int ph = 0; ph < 2; ++ph) {       // p-chunks of 5: 10-deep ds ILP
                    float4 tw0[5], tw1[5];
#pragma unroll
                    for (int pp = 0; pp < 5; ++pp) {
                        const int p  = ph * 5 + pp;
                        const int o0 = (yi * 8) ^ xq[p >> 1];
                        tw0[pp] = *(const float4*)(tb + p * 64 + o0);
                        tw1[pp] = *(const float4*)(tb + p * 64 + (o0 ^ 4));
                    }
#pragma unroll
                    for (int pp = 0; pp < 5; ++pp) {
                        const int p = ph * 5 + pp;
                        if (p < 9) CHAIN(ar[0][yi][0], ar[0][yi][1], tw0[pp], tw1[pp], acc0[p]);
                        if (p > 0) CHAIN(ar[1][yi][0], ar[1][yi][1], tw0[pp], tw1[pp], acc1[p - 1]);
                    }
                }
            }
        }
    }
    // ---- y-half merge via LDS (aliases Tt, barrier-protected) ----
    __syncthreads();
    double* yred = (double*)lds;                     // 108 pairs * 18 f64 = 3888 dw
    const int pairId = (it * NBG + bg) * 9 + dy;
    if (act && yh == 1) {
        double* d = yred + pairId * 18;
#pragma unroll
        for (int k = 0; k < 9; ++k) { d[k] = acc0[k]; d[9 + k] = acc1[k]; }
    }
    __syncthreads();
    double* redc = (double*)(lds + 8192);            // 216 f64 = 432 dw
    int*    redk = (int*)(lds + 8192 + 432);         // 216 int
    if (act && yh == 0) {
        const double* d = yred + pairId * 18;
#pragma unroll
        for (int k = 0; k < 9; ++k) { acc0[k] += d[k]; acc1[k] += d[9 + k]; }
        // stage-1 argmin over dx (ascending, strict < -> first-k ties)
#pragma unroll
        for (int a2 = 0; a2 < 2; ++a2) {
            double bc = 1e300; int bk = -1;
            const int jb = j0 + 2 * bg + a2;
#pragma unroll
            for (int dxi = 0; dxi < 9; ++dxi) {
                const int gj = jb + dxi - 4;
                const double c = a2 ? acc1[dxi] : acc0[dxi];
                if (dyValid && gj >= 0 && gj < GW && c < bc) { bc = c; bk = dy * 9 + dxi; }
            }
            redc[(it * 9 + dy) * JT + 2 * bg + a2] = bc;
            redk[(it * 9 + dy) * JT + 2 * bg + a2] = bk;
        }
    }
    __syncthreads();
    // ---- stage-2 argmin over dy (ascending, strict <) ----
    if (tid < IT * JT) {
        const int it2 = tid / JT, jt = tid % JT;
        if (i0 + it2 < GH) {
            double c = 1e300; int k = -1;
#pragma unroll
            for (int dyi = 0; dyi < 9; ++dyi) {
                const double v = redc[(it2 * 9 + dyi) * JT + jt];
                if (v < c) { c = v; k = redk[(it2 * 9 + dyi) * JT + jt]; }
            }
            const int dyi = k / 9, dxi = k % 9;
            const int bi = i0 + it2 + dyi - 4;
            const int bj = j0 + jt + dxi - 4;
            bestidx[(i0 + it2) * GW + j0 + jt] = (bi << 8) | bj;
        }
    }
}

__global__ void __launch_bounds__(256) hbma_gather_kernel(const float* __restrict__ A,
                                                          const int* __restrict__ bestidx,
                                                          float* __restrict__ out) {
    const int tid = blockIdx.x * 256 + threadIdx.x;
    const int q   = tid / (HWPX / 4);
    const int rem = tid % (HWPX / 4);
    const int py  = rem / (WW / 4);
    const int c4  = rem % (WW / 4);
    const int i = py >> 3, y = py & 7;
    const int j = c4 >> 1, xh = (c4 & 1) * 4;
    const int idx = bestidx[i * GW + j];
    const int bi = idx >> 8, bj = idx & 255;
    const float4 v = *(const float4*)(A + (size_t)q * HWPX + (size_t)(bi * 8 + y) * WW + bj * 8 + xh);
    *(float4*)(out + (size_t)q * HWPX + (size_t)py * WW + c4 * 4) = v;
}

extern "C" void kernel_launch(void* const* d_in, const int* in_sizes, int n_in,
                              void* d_out, int out_size, void* d_ws, size_t ws_size,
                              hipStream_t stream) {
    const float* A = (const float*)d_in[0];
    const float* T = (const float*)d_in[1];
    float* out = (float*)d_out;
    int* bestidx = (int*)d_ws;

    hipFuncSetAttribute((const void*)hbma_cost_kernel,
                        hipFuncAttributeMaxDynamicSharedMemorySize, TT_DW * 4);

    hipLaunchKernelGGL(hbma_cost_kernel, dim3(NWG), dim3(NTHR), TT_DW * 4, stream,
                       A, T, bestidx);

    const int total4 = (NP * HWPX) / 4;
    hipLaunchKernelGGL(hbma_gather_kernel, dim3(total4 / 256), dim3(256), 0, stream,
                       A, bestidx, out);
}

// Round 12
// 252.277 us; speedup vs baseline: 2.0782x; 1.0035x over previous
//
#include <hip/hip_runtime.h>

#define GH 135
#define GW 240
#define HH 1080
#define WW 1920
#define HWPX (HH*WW)
#define NP 12
#define IT 2               // anchor block-rows per WG (i-strip)
#define JT 12              // anchor blocks (j) per WG
#define NBG 6              // anchor pairs per it-row
#define NIG 68             // ceil(GH/IT)
#define NJG 20             // GW/JT
#define TROWS (IT+8)       // 10 staged target block-rows
#define TBLK (JT+8)        // 20 staged target blocks per dy-row
#define DSTR (TBLK*64+8)   // 1288 dw: 16B-aligned; dr*1288 %32 = 8*dr -> +2 QUAD
                           // rotation per row. r11 had +4 (1 quad): it-pairs
                           // sharing a row gave hist [3,4,3,2,...] (4-way spots,
                           // 1.33x/read = 1.74e7 cyc). With rot2: [3,3,3,3,...]
                           // uniform -> 64-lane b128 hits each quad exactly 8x
                           // = HW minimum (zero excess conflict).
#define UNITS_ROW (TBLK*16)// 320 16B-units per dy-row (= exactly 5 waves)
#define UNITS_TOT (TROWS*UNITS_ROW) // 3200
#define NTHR 256
#define NACT 216           // 9 dy * (2 it * 6 bg * 2 yh)
#define TT_DW (TROWS*DSTR) // 12880 dw = 51520 B -> 3 WG/CU (154.6KB <= 160KB)
#define NWG (NIG*NJG)      // 1360 = 8*170 (XCD-exact)

// OCCUPANCY LAW (fit r5-r10): VGPR cap = 256/min_waves_per_EU; resident
// waves/SIMD = floor(256/VGPR). 84 regs -> 3 waves/SIMD -> 3 WG/CU.
// Staging: async __builtin_amdgcn_global_load_lds (r11, proven): linear LDS
// dest units (wave-uniform base + lane*16), inverse-swizzled + CLAMPED global
// src (garbage lands only in argmin-masked slots).
// Swizzled storage (bijective involution, proven r5):
//   stored(blk,y,xh) = blk*64 + ((y*8+xh) ^ 4*kb ^ 16*(y>>2)), kb=(blk>>1)&7

// 8-px fp32 chain + f64 accumulate (argmin-exact vs np reference, proven r1-r11)
#define CHAIN(AV0, AV1, T0, T1, ACC) do { \
    float _d = (AV0).x - (T0).x; float _s = _d*_d; \
    _d = (AV0).y - (T0).y; _s = fmaf(_d,_d,_s); \
    _d = (AV0).z - (T0).z; _s = fmaf(_d,_d,_s); \
    _d = (AV0).w - (T0).w; _s = fmaf(_d,_d,_s); \
    _d = (AV1).x - (T1).x; _s = fmaf(_d,_d,_s); \
    _d = (AV1).y - (T1).y; _s = fmaf(_d,_d,_s); \
    _d = (AV1).z - (T1).z; _s = fmaf(_d,_d,_s); \
    _d = (AV1).w - (T1).w; _s = fmaf(_d,_d,_s); \
    (ACC) += (double)_s; } while(0)

__device__ __forceinline__ void async_copy16(const float* gp, float* lp) {
#if __has_builtin(__builtin_amdgcn_global_load_lds)
    __builtin_amdgcn_global_load_lds(
        (const __attribute__((address_space(1))) void*)gp,
        (__attribute__((address_space(3))) void*)lp, 16, 0, 0);
#else
    *(float4*)lp = *(const float4*)gp;
#endif
}

__global__ void __launch_bounds__(NTHR, 3)
hbma_cost_kernel(const float* __restrict__ A, const float* __restrict__ T,
                 int* __restrict__ bestidx) {
    extern __shared__ float lds[];
    float* Tt = lds;

    // XCD swizzle: 1360 WGs = 8 XCDs x 170
    const int lin = blockIdx.x;
    const int g   = (lin & 7) * (NWG / 8) + (lin >> 3);
    const int ig  = g % NIG, jg = g / NIG;
    const int i0  = ig * IT;
    const int j0  = jg * JT;

    const int tid = threadIdx.x;
    const int dy  = tid / 24;          // 0..8
    const int rem = tid % 24;
    const int it  = rem / 12;          // 0..1
    const int r2  = rem % 12;
    const int bg  = r2 >> 1;           // 0..5 (anchor pair)
    const int yh  = r2 & 1;            // y-half
    const bool act = (tid < NACT);
    const int i   = i0 + it;
    const int gi  = i + dy - 4;
    const bool dyValid = act && (i < GH) && (gi >= 0) && (gi < GH);
    const int dr  = it + dy;           // staged row index 0..9

    int xq[5];                         // per p-pair h: 4*((bg+h)&7) ^ 16*yh
#pragma unroll
    for (int h = 0; h < 5; ++h) xq[h] = (((bg + h) & 7) * 4) ^ (yh << 4);

    double acc0[9], acc1[9];
#pragma unroll
    for (int d = 0; d < 9; ++d) { acc0[d] = 0.0; acc1[d] = 0.0; }

    const int gy0 = (i0 - 4) * 8;
    const int gx0 = (j0 - 4) * 8;

    for (int q = 0; q < NP; ++q) {
        const float* Tq = T + (size_t)q * HWPX;
        const float* Aq = A + (size_t)q * HWPX;
        __syncthreads();               // prev compute done before LDS overwrite
        // ---- stage target halo: async global->LDS DMA (linear dest units),
        //      inverse-swizzled + clamped global src; no regs, no ds_writes ----
        for (int w = tid; w < UNITS_TOT; w += NTHR) {
            const int dyr = w / UNITS_ROW;
            const int u   = w - dyr * UNITS_ROW;    // 16B unit within dy-row
            const int blk = u >> 4, v = u & 15;
            const int kb  = (blk >> 1) & 7;
            const int yh2 = v >> 3;
            const int m3  = (v & 7) ^ kb ^ (yh2 << 2);
            const int y   = (yh2 << 2) + (m3 >> 1);
            const int xh4 = m3 & 1;
            int gy = gy0 + dyr * 8 + y;
            int gx = gx0 + blk * 8 + xh4 * 4;
            gy = min(max(gy, 0), HH - 1);           // clamp: all lanes active,
            gx = min(max(gx, 0), WW - 4);           // garbage slots argmin-masked
            async_copy16(Tq + (size_t)gy * WW + gx, Tt + dyr * DSTR + u * 4);
        }
        // ---- anchor rows -> registers (issue overlaps in-flight DMA) ----
        float4 ar[2][4][2];
        if (act && i < GH) {
#pragma unroll
            for (int a2 = 0; a2 < 2; ++a2) {
                const float* ap = Aq + (size_t)(j0 + 2 * bg + a2) * 8;
#pragma unroll
                for (int yi = 0; yi < 4; ++yi) {
                    const float* row = ap + (size_t)(i * 8 + yh * 4 + yi) * WW;
                    ar[a2][yi][0] = *(const float4*)(row);
                    ar[a2][yi][1] = *(const float4*)(row + 4);
                }
            }
        }
        __syncthreads();               // compiler drains vmcnt(0) here: DMA landed
        // ---- SSD: sliding 10-block window serves 2 anchors x 9 dx ----
        if (dyValid) {
            const float* tb = Tt + dr * DSTR + bg * 128 + yh * 32;
#pragma unroll
            for (int yi = 0; yi < 4; ++yi) {
#pragma unroll
                for (int ph = 0; ph < 2; ++ph) {       // p-chunks of 5: 10-deep ds ILP
                    float4 tw0[5], tw1[5];
#pragma unroll
                    for (int pp = 0; pp < 5; ++pp) {
                        const int p  = ph * 5 + pp;
                        const int o0 = (yi * 8) ^ xq[p >> 1];
                        tw0[pp] = *(const float4*)(tb + p * 64 + o0);
                        tw1[pp] = *(const float4*)(tb + p * 64 + (o0 ^ 4));
                    }
#pragma unroll
                    for (int pp = 0; pp < 5; ++pp) {
                        const int p = ph * 5 + pp;
                        if (p < 9) CHAIN(ar[0][yi][0], ar[0][yi][1], tw0[pp], tw1[pp], acc0[p]);
                        if (p > 0) CHAIN(ar[1][yi][0], ar[1][yi][1], tw0[pp], tw1[pp], acc1[p - 1]);
                    }
                }
            }
        }
    }
    // ---- y-half merge via LDS (aliases Tt, barrier-protected) ----
    __syncthreads();
    double* yred = (double*)lds;                     // 108 pairs * 18 f64 = 3888 dw
    const int pairId = (it * NBG + bg) * 9 + dy;
    if (act && yh == 1) {
        double* d = yred + pairId * 18;
#pragma unroll
        for (int k = 0; k < 9; ++k) { d[k] = acc0[k]; d[9 + k] = acc1[k]; }
    }
    __syncthreads();
    double* redc = (double*)(lds + 8192);            // 216 f64 = 432 dw
    int*    redk = (int*)(lds + 8192 + 432);         // 216 int
    if (act && yh == 0) {
        const double* d = yred + pairId * 18;
#pragma unroll
        for (int k = 0; k < 9; ++k) { acc0[k] += d[k]; acc1[k] += d[9 + k]; }
        // stage-1 argmin over dx (ascending, strict < -> first-k ties)
#pragma unroll
        for (int a2 = 0; a2 < 2; ++a2) {
            double bc = 1e300; int bk = -1;
            const int jb = j0 + 2 * bg + a2;
#pragma unroll
            for (int dxi = 0; dxi < 9; ++dxi) {
                const int gj = jb + dxi - 4;
                const double c = a2 ? acc1[dxi] : acc0[dxi];
                if (dyValid && gj >= 0 && gj < GW && c < bc) { bc = c; bk = dy * 9 + dxi; }
            }
            redc[(it * 9 + dy) * JT + 2 * bg + a2] = bc;
            redk[(it * 9 + dy) * JT + 2 * bg + a2] = bk;
        }
    }
    __syncthreads();
    // ---- stage-2 argmin over dy (ascending, strict <) ----
    if (tid < IT * JT) {
        const int it2 = tid / JT, jt = tid % JT;
        if (i0 + it2 < GH) {
            double c = 1e300; int k = -1;
#pragma unroll
            for (int dyi = 0; dyi < 9; ++dyi) {
                const double v = redc[(it2 * 9 + dyi) * JT + jt];
                if (v < c) { c = v; k = redk[(it2 * 9 + dyi) * JT + jt]; }
            }
            const int dyi = k / 9, dxi = k % 9;
            const int bi = i0 + it2 + dyi - 4;
            const int bj = j0 + jt + dxi - 4;
            bestidx[(i0 + it2) * GW + j0 + jt] = (bi << 8) | bj;
        }
    }
}

__global__ void __launch_bounds__(256) hbma_gather_kernel(const float* __restrict__ A,
                                                          const int* __restrict__ bestidx,
                                                          float* __restrict__ out) {
    const int tid = blockIdx.x * 256 + threadIdx.x;
    const int q   = tid / (HWPX / 4);
    const int rem = tid % (HWPX / 4);
    const int py  = rem / (WW / 4);
    const int c4  = rem % (WW / 4);
    const int i = py >> 3, y = py & 7;
    const int j = c4 >> 1, xh = (c4 & 1) * 4;
    const int idx = bestidx[i * GW + j];
    const int bi = idx >> 8, bj = idx & 255;
    const float4 v = *(const float4*)(A + (size_t)q * HWPX + (size_t)(bi * 8 + y) * WW + bj * 8 + xh);
    *(float4*)(out + (size_t)q * HWPX + (size_t)py * WW + c4 * 4) = v;
}

extern "C" void kernel_launch(void* const* d_in, const int* in_sizes, int n_in,
                              void* d_out, int out_size, void* d_ws, size_t ws_size,
                              hipStream_t stream) {
    const float* A = (const float*)d_in[0];
    const float* T = (const float*)d_in[1];
    float* out = (float*)d_out;
    int* bestidx = (int*)d_ws;

    hipFuncSetAttribute((const void*)hbma_cost_kernel,
                        hipFuncAttributeMaxDynamicSharedMemorySize, TT_DW * 4);

    hipLaunchKernelGGL(hbma_cost_kernel, dim3(NWG), dim3(NTHR), TT_DW * 4, stream,
                       A, T, bestidx);

    const int total4 = (NP * HWPX) / 4;
    hipLaunchKernelGGL(hbma_gather_kernel, dim3(total4 / 256), dim3(256), 0, stream,
                       A, bestidx, out);
}

// Round 13
// 244.063 us; speedup vs baseline: 2.1481x; 1.0337x over previous
//
#include <hip/hip_runtime.h>

#define GH 135
#define GW 240
#define HH 1080
#define WW 1920
#define HWPX (HH*WW)
#define NP 12
#define IT 4               // anchor block-rows per WG
#define JT 12              // anchor blocks (j) per WG
#define NBG 6              // anchor pairs per it-row
#define NIG 34             // ceil(GH/IT)
#define NJG 20             // GW/JT
#define TROWS (IT+8)       // 12 staged target block-rows
#define TBLK (JT+8)        // 20 staged target blocks per dy-row
#define DSTR (TBLK*64+8)   // 1288 dw: +2 quad rotation per row (proven r12)
#define UNITS_ROW (TBLK*16)// 320 = 5 waves exactly
#define UNITS_TOT (TROWS*UNITS_ROW) // 3840
#define ASTR (JT*64+8)     // 776 dw anchor row stride (+2 quad rot, same scheme)
#define AUNITS_ROW (JT*16) // 192 = 3 waves exactly
#define AUNITS_TOT (IT*AUNITS_ROW) // 768
#define NTHR 512
#define NACT 432           // 9 dy * (4 it * 6 bg * 2 yh)
#define TT_DW (TROWS*DSTR) // 15456 dw = 61824 B per target buffer
#define AT_DW (IT*ASTR)    // 3104 dw = 12416 B per anchor buffer
#define LDS_DW (2*TT_DW + 2*AT_DW) // 37120 dw = 148480 B <= 160KB
#define NWG (NIG*NJG)      // 680 = 8*85 (XCD-exact)

// r12 lesson: no pipe >50% busy; 3 in-phase WGs serialize stage<->compute.
// This round: DOUBLE-BUFFERED single-WG pipeline (T3-lite): stage plane q+1
// (pure global_load_lds DMA, ~10 issue-only instrs) BEFORE compute(q); the
// only vmcnt wait is the end-of-iter barrier's auto-drain -> DMA latency
// hides under the whole compute phase. Anchors move to LDS (DMA'd, swizzled)
// so compute has ZERO vmem ops. Occupancy law (r5-r10): (512,2) -> cap 128
// VGPR; 1 WG/CU (LDS 148.5KB), 8 waves, 2/SIMD.
// Swizzled storage (bijective involution, proven r5/r12), per block-row:
//   stored(blk,y,xh) = blk*64 + ((y*8+xh) ^ 4*kb ^ 16*(y>>2)), kb=(blk>>1)&7
// Write side LINEAR DMA units; global src inverse-swizzled + clamped.

// 8-px fp32 chain + f64 accumulate (argmin-exact vs np reference, proven r1-r12)
#define CHAIN(AV0, AV1, T0, T1, ACC) do { \
    float _d = (AV0).x - (T0).x; float _s = _d*_d; \
    _d = (AV0).y - (T0).y; _s = fmaf(_d,_d,_s); \
    _d = (AV0).z - (T0).z; _s = fmaf(_d,_d,_s); \
    _d = (AV0).w - (T0).w; _s = fmaf(_d,_d,_s); \
    _d = (AV1).x - (T1).x; _s = fmaf(_d,_d,_s); \
    _d = (AV1).y - (T1).y; _s = fmaf(_d,_d,_s); \
    _d = (AV1).z - (T1).z; _s = fmaf(_d,_d,_s); \
    _d = (AV1).w - (T1).w; _s = fmaf(_d,_d,_s); \
    (ACC) += (double)_s; } while(0)

__device__ __forceinline__ void async_copy16(const float* gp, float* lp) {
#if __has_builtin(__builtin_amdgcn_global_load_lds)
    __builtin_amdgcn_global_load_lds(
        (const __attribute__((address_space(1))) void*)gp,
        (__attribute__((address_space(3))) void*)lp, 16, 0, 0);
#else
    *(float4*)lp = *(const float4*)gp;
#endif
}

// issue-only staging of one plane (target halo + anchor tile) into one buffer
__device__ __forceinline__ void stage_plane(const float* __restrict__ Tq,
                                            const float* __restrict__ Aq,
                                            float* tdst, float* adst,
                                            int tid, int gy0, int gx0,
                                            int i0, int j0) {
    for (int w = tid; w < UNITS_TOT; w += NTHR) {      // 7-8 iters, wave-uniform tail
        const int dyr = w / UNITS_ROW;
        const int u   = w - dyr * UNITS_ROW;
        const int blk = u >> 4, v = u & 15;
        const int kb  = (blk >> 1) & 7;
        const int yh2 = v >> 3;
        const int m3  = (v & 7) ^ kb ^ (yh2 << 2);
        const int y   = (yh2 << 2) + (m3 >> 1);
        const int xh4 = m3 & 1;
        int gy = gy0 + dyr * 8 + y;
        int gx = gx0 + blk * 8 + xh4 * 4;
        gy = min(max(gy, 0), HH - 1);                  // clamp: garbage slots are
        gx = min(max(gx, 0), WW - 4);                  // argmin-masked (proven r11)
        async_copy16(Tq + (size_t)gy * WW + gx, tdst + dyr * DSTR + u * 4);
    }
    for (int w = tid; w < AUNITS_TOT; w += NTHR) {     // 1-2 iters, wave-uniform tail
        const int itr = w / AUNITS_ROW;
        const int u   = w - itr * AUNITS_ROW;
        const int blk = u >> 4, v = u & 15;
        const int kb  = (blk >> 1) & 7;
        const int yh2 = v >> 3;
        const int m3  = (v & 7) ^ kb ^ (yh2 << 2);
        const int y   = (yh2 << 2) + (m3 >> 1);
        const int xh4 = m3 & 1;
        int gy = (i0 + itr) * 8 + y;
        gy = min(gy, HH - 1);                          // last-strip clamp (i>=GH guarded)
        const int gx = (j0 + blk) * 8 + xh4 * 4;       // always in-bounds
        async_copy16(Aq + (size_t)gy * WW + gx, adst + itr * ASTR + u * 4);
    }
}

__global__ void __launch_bounds__(NTHR, 2)
hbma_cost_kernel(const float* __restrict__ A, const float* __restrict__ T,
                 int* __restrict__ bestidx) {
    extern __shared__ float lds[];

    // XCD swizzle: 680 WGs = 8 XCDs x 85
    const int lin = blockIdx.x;
    const int g   = (lin & 7) * (NWG / 8) + (lin >> 3);
    const int ig  = g % NIG, jg = g / NIG;
    const int i0  = ig * IT;
    const int j0  = jg * JT;

    const int tid = threadIdx.x;
    const int dy  = tid / 48;          // 0..8 for active threads
    const int rem = tid % 48;
    const int it  = rem / 12;          // 0..3
    const int r2  = rem % 12;
    const int bg  = r2 >> 1;           // 0..5 (anchor pair)
    const int yh  = r2 & 1;            // y-half
    const bool act = (tid < NACT);
    const int i   = i0 + it;           // may be >= GH on last strip (guarded)
    const int gi  = i + dy - 4;
    const bool dyValid = act && (i < GH) && (gi >= 0) && (gi < GH);
    const int dr  = it + dy;           // staged row index 0..11

    int xq[5];                         // target read XOR per p-pair h
#pragma unroll
    for (int h = 0; h < 5; ++h) xq[h] = (((bg + h) & 7) * 4) ^ (yh << 4);
    const int xa = (bg * 4) ^ (yh << 4);   // anchor read XOR (kb' = bg)

    double acc0[9], acc1[9];
#pragma unroll
    for (int d = 0; d < 9; ++d) { acc0[d] = 0.0; acc1[d] = 0.0; }

    const int gy0 = (i0 - 4) * 8;
    const int gx0 = (j0 - 4) * 8;

    // ---- prologue: stage plane 0 into buffer 0, drain, sync ----
    stage_plane(T, A, lds, lds + 2 * TT_DW, tid, gy0, gx0, i0, j0);
    __syncthreads();                   // auto vmcnt(0): DMA landed

    for (int q = 0; q < NP; ++q) {
        const int cur = q & 1;
        // ---- issue next-plane DMAs into the other buffer (no waits here) ----
        if (q + 1 < NP)
            stage_plane(T + (size_t)(q + 1) * HWPX, A + (size_t)(q + 1) * HWPX,
                        lds + (cur ^ 1) * TT_DW,
                        lds + 2 * TT_DW + (cur ^ 1) * AT_DW,
                        tid, gy0, gx0, i0, j0);
        // ---- compute plane q: pure LDS + VALU (DMA latency hides under it) ----
        if (dyValid) {
            const float* tb = lds + cur * TT_DW + dr * DSTR + bg * 128 + yh * 32;
            const float* ab = lds + 2 * TT_DW + cur * AT_DW
                            + it * ASTR + (2 * bg) * 64 + yh * 32;
#pragma unroll
            for (int yi = 0; yi < 4; ++yi) {
                float4 aw[2][2];
                const int oA = (yi * 8) ^ xa;
                aw[0][0] = *(const float4*)(ab + oA);
                aw[0][1] = *(const float4*)(ab + (oA ^ 4));
                aw[1][0] = *(const float4*)(ab + 64 + oA);
                aw[1][1] = *(const float4*)(ab + 64 + (oA ^ 4));
#pragma unroll
                for (int ph = 0; ph < 2; ++ph) {       // p-chunks of 5: 10-deep ds ILP
                    float4 tw0[5], tw1[5];
#pragma unroll
                    for (int pp = 0; pp < 5; ++pp) {
                        const int p  = ph * 5 + pp;
                        const int o0 = (yi * 8) ^ xq[p >> 1];
                        tw0[pp] = *(const float4*)(tb + p * 64 + o0);
                        tw1[pp] = *(const float4*)(tb + p * 64 + (o0 ^ 4));
                    }
#pragma unroll
                    for (int pp = 0; pp < 5; ++pp) {
                        const int p = ph * 5 + pp;
                        if (p < 9) CHAIN(aw[0][0], aw[0][1], tw0[pp], tw1[pp], acc0[p]);
                        if (p > 0) CHAIN(aw[1][0], aw[1][1], tw0[pp], tw1[pp], acc1[p - 1]);
                    }
                }
            }
        }
        __syncthreads();               // auto vmcnt(0): next buffer landed; all
                                       // readers done before it is re-staged
    }
    // ---- y-half merge via LDS (aliases buffer 0, barrier-protected) ----
    __syncthreads();
    double* yred = (double*)lds;                     // 216 pairs * 18 f64 = 7776 dw
    const int pairId = (it * NBG + bg) * 9 + dy;
    if (act && yh == 1) {
        double* d = yred + pairId * 18;
#pragma unroll
        for (int k = 0; k < 9; ++k) { d[k] = acc0[k]; d[9 + k] = acc1[k]; }
    }
    __syncthreads();
    double* redc = (double*)(lds + 8192);            // 432 f64 = 864 dw
    int*    redk = (int*)(lds + 8192 + 864);         // 432 int
    if (act && yh == 0) {
        const double* d = yred + pairId * 18;
#pragma unroll
        for (int k = 0; k < 9; ++k) { acc0[k] += d[k]; acc1[k] += d[9 + k]; }
        // stage-1 argmin over dx (ascending, strict < -> first-k ties)
#pragma unroll
        for (int a2 = 0; a2 < 2; ++a2) {
            double bc = 1e300; int bk = -1;
            const int jb = j0 + 2 * bg + a2;
#pragma unroll
            for (int dxi = 0; dxi < 9; ++dxi) {
                const int gj = jb + dxi - 4;
                const double c = a2 ? acc1[dxi] : acc0[dxi];
                if (dyValid && gj >= 0 && gj < GW && c < bc) { bc = c; bk = dy * 9 + dxi; }
            }
            redc[(it * 9 + dy) * JT + 2 * bg + a2] = bc;
            redk[(it * 9 + dy) * JT + 2 * bg + a2] = bk;
        }
    }
    __syncthreads();
    // ---- stage-2 argmin over dy (ascending, strict <) ----
    if (tid < IT * JT) {
        const int it2 = tid / JT, jt = tid % JT;
        if (i0 + it2 < GH) {
            double c = 1e300; int k = -1;
#pragma unroll
            for (int dyi = 0; dyi < 9; ++dyi) {
                const double v = redc[(it2 * 9 + dyi) * JT + jt];
                if (v < c) { c = v; k = redk[(it2 * 9 + dyi) * JT + jt]; }
            }
            const int dyi = k / 9, dxi = k % 9;
            const int bi = i0 + it2 + dyi - 4;
            const int bj = j0 + jt + dxi - 4;
            bestidx[(i0 + it2) * GW + j0 + jt] = (bi << 8) | bj;
        }
    }
}

__global__ void __launch_bounds__(256) hbma_gather_kernel(const float* __restrict__ A,
                                                          const int* __restrict__ bestidx,
                                                          float* __restrict__ out) {
    const int tid = blockIdx.x * 256 + threadIdx.x;
    const int q   = tid / (HWPX / 4);
    const int rem = tid % (HWPX / 4);
    const int py  = rem / (WW / 4);
    const int c4  = rem % (WW / 4);
    const int i = py >> 3, y = py & 7;
    const int j = c4 >> 1, xh = (c4 & 1) * 4;
    const int idx = bestidx[i * GW + j];
    const int bi = idx >> 8, bj = idx & 255;
    const float4 v = *(const float4*)(A + (size_t)q * HWPX + (size_t)(bi * 8 + y) * WW + bj * 8 + xh);
    *(float4*)(out + (size_t)q * HWPX + (size_t)py * WW + c4 * 4) = v;
}

extern "C" void kernel_launch(void* const* d_in, const int* in_sizes, int n_in,
                              void* d_out, int out_size, void* d_ws, size_t ws_size,
                              hipStream_t stream) {
    const float* A = (const float*)d_in[0];
    const float* T = (const float*)d_in[1];
    float* out = (float*)d_out;
    int* bestidx = (int*)d_ws;

    hipFuncSetAttribute((const void*)hbma_cost_kernel,
                        hipFuncAttributeMaxDynamicSharedMemorySize, LDS_DW * 4);

    hipLaunchKernelGGL(hbma_cost_kernel, dim3(NWG), dim3(NTHR), LDS_DW * 4, stream,
                       A, T, bestidx);

    const int total4 = (NP * HWPX) / 4;
    hipLaunchKernelGGL(hbma_gather_kernel, dim3(total4 / 256), dim3(256), 0, stream,
                       A, bestidx, out);
}